// Round 1
// baseline (529.241 us; speedup 1.0000x reference)
//
#include <hip/hip_runtime.h>

#define N_NODES 4096
#define N_EDGES 524288
#define HID 64
#define NCHUNK 16
#define KCHUNK 256   // 4096 / NCHUNK
#define KTILE 64
#define QTILE 512

__device__ __forceinline__ float bcastf(float v, int l) {
    return __int_as_float(__builtin_amdgcn_readlane(__float_as_int(v), l));
}

__device__ __forceinline__ void wave_sum2(float& a, float& b) {
    #pragma unroll
    for (int off = 32; off > 0; off >>= 1) {
        a += __shfl_xor(a, off, 64);
        b += __shfl_xor(b, off, 64);
    }
}

// ---------------- xe = concat(x, emb[etype]) padded to 16 ----------------
__global__ void xe_kernel(const float* __restrict__ x, const float* __restrict__ emb,
                          const int* __restrict__ etype, float* __restrict__ xe) {
    int tid = blockIdx.x * blockDim.x + threadIdx.x;
    if (tid >= N_NODES * 16) return;
    int n = tid >> 4, i = tid & 15;
    float v = 0.f;
    if (i < 6) v = x[n * 6 + i];
    else if (i < 14) v = emb[etype[n] * 8 + (i - 6)];
    xe[tid] = v;
}

// ---------------- edge MLP + scatter-add: wave per edge ----------------
__global__ void edge_kernel(const float* __restrict__ xe, const float* __restrict__ edge_attr,
                            const int* __restrict__ ei,
                            const float* __restrict__ w1, const float* __restrict__ b1,
                            const float* __restrict__ w2, const float* __restrict__ b2,
                            const float* __restrict__ g, const float* __restrict__ bln,
                            float* __restrict__ h) {
    int lane = threadIdx.x & 63;
    int wid = (blockIdx.x * (blockDim.x >> 6)) + (threadIdx.x >> 6);
    int nw = gridDim.x * (blockDim.x >> 6);
    int j = lane;
    float w1r[15];
    #pragma unroll
    for (int i = 0; i < 15; i++) w1r[i] = w1[j * 15 + i];
    float w2r[64];
    #pragma unroll
    for (int k = 0; k < 64; k++) w2r[k] = w2[j * 64 + k];
    float b1j = b1[j], b2j = b2[j], gj = g[j], bj = bln[j];

    int e = wid;
    if (e >= N_EDGES) return;
    int src = ei[e];
    int dst = ei[N_EDGES + e];
    float inval = (lane < 14) ? xe[src * 16 + lane] : edge_attr[e];

    while (true) {
        // software-pipelined prefetch of next edge
        int e2 = e + nw;
        bool more = (e2 < N_EDGES);
        int src2 = 0, dst2 = 0;
        float inval2 = 0.f;
        if (more) {
            src2 = ei[e2];
            dst2 = ei[N_EDGES + e2];
            inval2 = (lane < 14) ? xe[src2 * 16 + lane] : edge_attr[e2];
        }
        // layer 1: out_j = b1[j] + sum_i w1[j][i] * in[i]
        float acc = b1j;
        #pragma unroll
        for (int i = 0; i < 15; i++) acc = fmaf(w1r[i], bcastf(inval, i), acc);
        float r = fmaxf(acc, 0.f);
        float s = r, s2 = r * r;
        wave_sum2(s, s2);
        float mean = s * (1.f / 64.f);
        float var = s2 * (1.f / 64.f) - mean * mean;
        float rs = rsqrtf(var + 1e-5f);
        float y = (r - mean) * rs * gj + bj;
        // layer 2
        float acc2 = b2j;
        #pragma unroll
        for (int k = 0; k < 64; k++) acc2 = fmaf(w2r[k], bcastf(y, k), acc2);
        float r2 = fmaxf(acc2, 0.f);
        float t = r2, t2 = r2 * r2;
        wave_sum2(t, t2);
        float mean2 = t * (1.f / 64.f);
        float var2 = t2 * (1.f / 64.f) - mean2 * mean2;
        float rs2 = rsqrtf(var2 + 1e-5f);
        float z = (r2 - mean2) * rs2 * gj + bj;
        atomicAdd(&h[dst * 64 + j], z);
        if (!more) break;
        e = e2; src = src2; dst = dst2; inval = inval2;
        (void)src;
    }
}

// ---------------- qkv projection: wave per node ----------------
__global__ void qkv_kernel(const float* __restrict__ h, const float* __restrict__ w,
                           const float* __restrict__ b, float* __restrict__ qb,
                           float* __restrict__ kb, float* __restrict__ vb) {
    __shared__ float wl[192 * 65];
    for (int i = threadIdx.x; i < 192 * 64; i += blockDim.x) {
        int r = i >> 6, c = i & 63;
        wl[r * 65 + c] = w[i];
    }
    __syncthreads();
    int lane = threadIdx.x & 63;
    int n = blockIdx.x * 4 + (threadIdx.x >> 6);
    int j = lane;
    float hj = h[n * 64 + j];
    float aq = b[j], ak = b[j + 64], av = b[j + 128];
    #pragma unroll
    for (int k = 0; k < 64; k++) {
        float hk = bcastf(hj, k);
        aq = fmaf(wl[j * 65 + k], hk, aq);
        ak = fmaf(wl[(j + 64) * 65 + k], hk, ak);
        av = fmaf(wl[(j + 128) * 65 + k], hk, av);
    }
    int head = j >> 4, d = j & 15;
    int o = (head * N_NODES + n) * 16 + d;
    qb[o] = aq * 0.25f;  // fold 1/sqrt(16) into q
    kb[o] = ak;
    vb[o] = av;
}

// ---------------- attention phase 1: per (head, qtile, kchunk) partials ----------------
__device__ __forceinline__ float dot16(const float* a, const float* b) {
    float s0 = 0, s1 = 0, s2 = 0, s3 = 0;
    #pragma unroll
    for (int d = 0; d < 16; d += 4) {
        s0 = fmaf(a[d], b[d], s0);
        s1 = fmaf(a[d + 1], b[d + 1], s1);
        s2 = fmaf(a[d + 2], b[d + 2], s2);
        s3 = fmaf(a[d + 3], b[d + 3], s3);
    }
    return (s0 + s1) + (s2 + s3);
}

__device__ __forceinline__ void online_upd(float s, float& m, float& l, float* o,
                                           const float* vrow) {
    if (s > m) {
        float c = __expf(m - s);
        m = s;
        l = l * c + 1.f;
        #pragma unroll
        for (int d = 0; d < 16; d++) o[d] = fmaf(o[d], c, vrow[d]);
    } else {
        float p = __expf(s - m);
        l += p;
        #pragma unroll
        for (int d = 0; d < 16; d++) o[d] = fmaf(p, vrow[d], o[d]);
    }
}

__global__ void attn_p1(const float* __restrict__ qB, const float* __restrict__ kB,
                        const float* __restrict__ vB, float* __restrict__ part) {
    __shared__ float Ks[KTILE][16];
    __shared__ float Vs[KTILE][16];
    int head = blockIdx.x, qt = blockIdx.y, kc = blockIdx.z;
    int t = threadIdx.x;
    int q0 = qt * QTILE + t;
    int q1 = q0 + 256;
    const float* qh = qB + (size_t)head * N_NODES * 16;
    float qa[16], qc[16];
    #pragma unroll
    for (int d4 = 0; d4 < 4; d4++) {
        float4 f = ((const float4*)(qh + q0 * 16))[d4];
        qa[d4 * 4] = f.x; qa[d4 * 4 + 1] = f.y; qa[d4 * 4 + 2] = f.z; qa[d4 * 4 + 3] = f.w;
        float4 g = ((const float4*)(qh + q1 * 16))[d4];
        qc[d4 * 4] = g.x; qc[d4 * 4 + 1] = g.y; qc[d4 * 4 + 2] = g.z; qc[d4 * 4 + 3] = g.w;
    }
    float m0 = -3e38f, l0 = 0.f, o0[16];
    float m1 = -3e38f, l1 = 0.f, o1[16];
    #pragma unroll
    for (int d = 0; d < 16; d++) { o0[d] = 0.f; o1[d] = 0.f; }

    const float* kh = kB + ((size_t)head * N_NODES + kc * KCHUNK) * 16;
    const float* vh = vB + ((size_t)head * N_NODES + kc * KCHUNK) * 16;
    int sr = t >> 2, sc = (t & 3) << 2;

    for (int kt = 0; kt < KCHUNK; kt += KTILE) {
        __syncthreads();
        *(float4*)&Ks[sr][sc] = *(const float4*)&kh[(kt + sr) * 16 + sc];
        *(float4*)&Vs[sr][sc] = *(const float4*)&vh[(kt + sr) * 16 + sc];
        __syncthreads();
        for (int kk = 0; kk < KTILE; kk++) {
            float krow[16], vrow[16];
            #pragma unroll
            for (int d4 = 0; d4 < 4; d4++) {
                float4 kf = ((const float4*)&Ks[kk][0])[d4];
                krow[d4 * 4] = kf.x; krow[d4 * 4 + 1] = kf.y;
                krow[d4 * 4 + 2] = kf.z; krow[d4 * 4 + 3] = kf.w;
                float4 vf = ((const float4*)&Vs[kk][0])[d4];
                vrow[d4 * 4] = vf.x; vrow[d4 * 4 + 1] = vf.y;
                vrow[d4 * 4 + 2] = vf.z; vrow[d4 * 4 + 3] = vf.w;
            }
            float s0 = dot16(qa, krow);
            float s1 = dot16(qc, krow);
            online_upd(s0, m0, l0, o0, vrow);
            online_upd(s1, m1, l1, o1, vrow);
        }
    }
    float* p0 = part + ((size_t)(head * NCHUNK + kc) * N_NODES + q0) * 18;
    float* p1 = part + ((size_t)(head * NCHUNK + kc) * N_NODES + q1) * 18;
    #pragma unroll
    for (int d = 0; d < 16; d++) { p0[d] = o0[d]; p1[d] = o1[d]; }
    p0[16] = m0; p0[17] = l0;
    p1[16] = m1; p1[17] = l1;
}

// ---------------- attention phase 2: merge chunks ----------------
__global__ void attn_merge(const float* __restrict__ part, float* __restrict__ o64) {
    int tid = blockIdx.x * blockDim.x + threadIdx.x;  // 16384
    int head = tid >> 12;
    int qg = tid & 4095;
    float M = -3e38f, L = 0.f, O[16];
    #pragma unroll
    for (int d = 0; d < 16; d++) O[d] = 0.f;
    for (int c = 0; c < NCHUNK; c++) {
        const float* p = part + ((size_t)(head * NCHUNK + c) * N_NODES + qg) * 18;
        float mc = p[16], lc = p[17];
        if (mc > M) {
            float s = __expf(M - mc);
            M = mc;
            L = L * s + lc;
            #pragma unroll
            for (int d = 0; d < 16; d++) O[d] = fmaf(O[d], s, p[d]);
        } else {
            float s = __expf(mc - M);
            L = fmaf(lc, s, L);
            #pragma unroll
            for (int d = 0; d < 16; d++) O[d] = fmaf(p[d], s, O[d]);
        }
    }
    float inv = 1.f / L;
    #pragma unroll
    for (int d = 0; d < 16; d++) o64[qg * 64 + head * 16 + d] = O[d] * inv;
}

// ---------------- out_proj + residual + LN + final linear: wave per node ----------------
__global__ void post_kernel(const float* __restrict__ h, const float* __restrict__ o64,
                            const float* __restrict__ opw, const float* __restrict__ opb,
                            const float* __restrict__ ag, const float* __restrict__ ab,
                            const float* __restrict__ ow, const float* __restrict__ ob,
                            float* __restrict__ out) {
    __shared__ float wl1[64 * 65];
    __shared__ float wl2[64 * 65];
    for (int i = threadIdx.x; i < 4096; i += blockDim.x) {
        int r = i >> 6, c = i & 63;
        wl1[r * 65 + c] = opw[i];
        wl2[r * 65 + c] = ow[i];
    }
    __syncthreads();
    int lane = threadIdx.x & 63;
    int n = blockIdx.x * 4 + (threadIdx.x >> 6);
    int j = lane;
    float oj = o64[n * 64 + j];
    float acc = opb[j];
    #pragma unroll
    for (int k = 0; k < 64; k++) acc = fmaf(wl1[j * 65 + k], bcastf(oj, k), acc);
    float r = h[n * 64 + j] + acc;
    float s = r, s2 = r * r;
    wave_sum2(s, s2);
    float mean = s * (1.f / 64.f);
    float var = s2 * (1.f / 64.f) - mean * mean;
    float hn = (r - mean) * rsqrtf(var + 1e-5f) * ag[j] + ab[j];
    float acc2 = ob[j];
    #pragma unroll
    for (int k = 0; k < 64; k++) acc2 = fmaf(wl2[j * 65 + k], bcastf(hn, k), acc2);
    out[n * 64 + j] = acc2;
}

extern "C" void kernel_launch(void* const* d_in, const int* in_sizes, int n_in,
                              void* d_out, int out_size, void* d_ws, size_t ws_size,
                              hipStream_t stream) {
    const float* x        = (const float*)d_in[0];
    const float* edge_attr= (const float*)d_in[1];
    const float* emb      = (const float*)d_in[2];
    const float* lin1_w   = (const float*)d_in[3];
    const float* lin1_b   = (const float*)d_in[4];
    const float* lay_w    = (const float*)d_in[5];
    const float* lay_b    = (const float*)d_in[6];
    const float* ln_g     = (const float*)d_in[7];
    const float* ln_b     = (const float*)d_in[8];
    const float* ipw      = (const float*)d_in[9];
    const float* ipb      = (const float*)d_in[10];
    const float* opw      = (const float*)d_in[11];
    const float* opb      = (const float*)d_in[12];
    const float* ang      = (const float*)d_in[13];
    const float* anb      = (const float*)d_in[14];
    const float* ow       = (const float*)d_in[15];
    const float* ob       = (const float*)d_in[16];
    const int*   ei       = (const int*)d_in[17];
    const int*   et       = (const int*)d_in[18];

    float* ws   = (float*)d_ws;
    float* xe   = ws;                    // 65536
    float* h    = xe + 65536;            // 262144
    float* qb   = h + 262144;            // 262144
    float* kb   = qb + 262144;           // 262144
    float* vb   = kb + 262144;           // 262144
    float* o64  = vb + 262144;           // 262144
    float* part = o64 + 262144;          // 4*16*4096*18 = 4718592

    hipMemsetAsync(h, 0, 262144 * sizeof(float), stream);
    xe_kernel<<<256, 256, 0, stream>>>(x, emb, et, xe);
    edge_kernel<<<2048, 256, 0, stream>>>(xe, edge_attr, ei, lin1_w, lin1_b,
                                          lay_w, lay_b, ln_g, ln_b, h);
    qkv_kernel<<<1024, 256, 0, stream>>>(h, ipw, ipb, qb, kb, vb);
    attn_p1<<<dim3(4, 8, 16), 256, 0, stream>>>(qb, kb, vb, part);
    attn_merge<<<64, 256, 0, stream>>>(part, o64);
    post_kernel<<<1024, 256, 0, stream>>>(h, o64, opw, opb, ang, anb, ow, ob,
                                          (float*)d_out);
}

// Round 2
// 359.571 us; speedup vs baseline: 1.4719x; 1.4719x over previous
//
#include <hip/hip_runtime.h>

#define N_NODES 4096
#define N_EDGES 524288
#define HID 64
#define NCHUNK 16
#define KCHUNK 256   // 4096 / NCHUNK
#define KTILE 64
#define QTILE 512

typedef short short8 __attribute__((ext_vector_type(8)));
typedef float f32x4 __attribute__((ext_vector_type(4)));

__device__ __forceinline__ float bcastf(float v, int l) {
    return __int_as_float(__builtin_amdgcn_readlane(__float_as_int(v), l));
}

__device__ __forceinline__ void wave_sum2(float& a, float& b) {
    #pragma unroll
    for (int off = 32; off > 0; off >>= 1) {
        a += __shfl_xor(a, off, 64);
        b += __shfl_xor(b, off, 64);
    }
}

__device__ __forceinline__ short f2bf(float f) {
    unsigned u = __float_as_uint(f);
    u = u + 0x7FFFu + ((u >> 16) & 1u);
    return (short)(u >> 16);
}
__device__ __forceinline__ float bf2f(short s) {
    return __uint_as_float(((unsigned)(unsigned short)s) << 16);
}

// ---------------- xe hi/lo bf16 planes: concat(x, emb[etype]) padded to 16 ----------------
__global__ void xe16_kernel(const float* __restrict__ x, const float* __restrict__ emb,
                            const int* __restrict__ etype,
                            unsigned short* __restrict__ xh, unsigned short* __restrict__ xl) {
    int tid = blockIdx.x * blockDim.x + threadIdx.x;
    if (tid >= N_NODES * 16) return;
    int n = tid >> 4, i = tid & 15;
    float v = 0.f;
    if (i < 6) v = x[n * 6 + i];
    else if (i < 14) v = emb[etype[n] * 8 + (i - 6)];
    short hi = f2bf(v);
    short lo = f2bf(v - bf2f(hi));
    xh[tid] = (unsigned short)hi;
    xl[tid] = (unsigned short)lo;
}

// ---------------- edge MLP via MFMA (hi/lo bf16 split, fp32-grade) ----------------
// 16 edges per wave-tile. Layer1: 12 MFMAs (4 groups x 3 split terms, K=32 pad of 15).
// LN in C-layout, LDS transpose, Layer2: 24 MFMAs (4 groups x 2 K-steps x 3 terms).
__global__ void __launch_bounds__(256) edge_mfma(
        const unsigned short* __restrict__ xh, const unsigned short* __restrict__ xl,
        const float* __restrict__ edge_attr, const int* __restrict__ ei,
        const float* __restrict__ w1, const float* __restrict__ b1,
        const float* __restrict__ w2, const float* __restrict__ b2,
        const float* __restrict__ lg, const float* __restrict__ lb,
        float* __restrict__ h) {
    __shared__ float Y[4][16 * 68];
    int lane = threadIdx.x & 63;
    int wv = threadIdx.x >> 6;
    int m = lane & 15;        // C col / A row / B col
    int q = lane >> 4;        // k-group
    float* Yw = Y[wv];

    // ---- persistent weight fragments ----
    short8 b1h[4], b1l[4];
    float w14[4], b1v[4], b2v[4], gam[4], bet[4];
    #pragma unroll
    for (int g = 0; g < 4; g++) {
        int row = g * 16 + m;
        #pragma unroll
        for (int j = 0; j < 8; j++) {
            int k = q * 8 + j;
            float w = (k < 15) ? w1[row * 15 + k] : 0.f;
            short hi = f2bf(w);
            b1h[g][j] = hi;
            b1l[g][j] = f2bf(w - bf2f(hi));
        }
        w14[g] = w1[row * 15 + 14];
        b1v[g] = b1[row];
        b2v[g] = b2[row];
        gam[g] = lg[row];
        bet[g] = lb[row];
    }
    short8 b2h[8], b2l[8];
    #pragma unroll
    for (int g = 0; g < 4; g++) {
        #pragma unroll
        for (int t = 0; t < 2; t++) {
            int idx = g * 2 + t;
            #pragma unroll
            for (int j = 0; j < 8; j++) {
                float w = w2[(g * 16 + m) * 64 + t * 32 + q * 8 + j];
                short hi = f2bf(w);
                b2h[idx][j] = hi;
                b2l[idx][j] = f2bf(w - bf2f(hi));
            }
        }
    }

    int wgid = blockIdx.x * 4 + wv;
    for (int it = 0; it < 16; it++) {
        int tile = wgid + it * 2048;
        int e0 = tile * 16;
        // ---- gather A1 (16 edges x K=32, only k<15 nonzero) ----
        int srcn = ei[e0 + m];
        short8 a1h = (short8)0, a1l = (short8)0;
        if (q < 2) {
            a1h = *(const short8*)(xh + srcn * 16 + q * 8);
            a1l = *(const short8*)(xl + srcn * 16 + q * 8);
        }
        float ea[4];
        #pragma unroll
        for (int i = 0; i < 4; i++) ea[i] = edge_attr[e0 + q * 4 + i];

        // ---- layer 1 MFMA ----
        f32x4 c1[4];
        #pragma unroll
        for (int g = 0; g < 4; g++) {
            f32x4 c = {0.f, 0.f, 0.f, 0.f};
            c = __builtin_amdgcn_mfma_f32_16x16x32_bf16(a1l, b1h[g], c, 0, 0, 0);
            c = __builtin_amdgcn_mfma_f32_16x16x32_bf16(a1h, b1l[g], c, 0, 0, 0);
            c = __builtin_amdgcn_mfma_f32_16x16x32_bf16(a1h, b1h[g], c, 0, 0, 0);
            c1[g] = c;
        }
        // ---- bias + edge_attr fold + relu + LN ----
        float s[4] = {0, 0, 0, 0}, s2[4] = {0, 0, 0, 0};
        float t1[4][4];
        #pragma unroll
        for (int g = 0; g < 4; g++) {
            #pragma unroll
            for (int i = 0; i < 4; i++) {
                float v = c1[g][i] + b1v[g] + w14[g] * ea[i];
                v = fmaxf(v, 0.f);
                t1[g][i] = v;
                s[i] += v;
                s2[i] += v * v;
            }
        }
        #pragma unroll
        for (int off = 1; off < 16; off <<= 1) {
            #pragma unroll
            for (int i = 0; i < 4; i++) {
                s[i] += __shfl_xor(s[i], off, 64);
                s2[i] += __shfl_xor(s2[i], off, 64);
            }
        }
        #pragma unroll
        for (int i = 0; i < 4; i++) {
            float mean = s[i] * (1.f / 64.f);
            float var = s2[i] * (1.f / 64.f) - mean * mean;
            float rs = rsqrtf(var + 1e-5f);
            s[i] = mean;   // reuse
            s2[i] = rs;
        }
        // ---- write y to LDS (C-layout -> [edge][feat], stride 68) ----
        #pragma unroll
        for (int g = 0; g < 4; g++) {
            #pragma unroll
            for (int i = 0; i < 4; i++) {
                float y = (t1[g][i] - s[i]) * s2[i] * gam[g] + bet[g];
                Yw[(q * 4 + i) * 68 + g * 16 + m] = y;
            }
        }
        // ---- read A2 frags (A-layout) + hi/lo split ----
        short8 a2h[2], a2l[2];
        #pragma unroll
        for (int t = 0; t < 2; t++) {
            #pragma unroll
            for (int j = 0; j < 8; j++) {
                float v = Yw[m * 68 + t * 32 + q * 8 + j];
                short hi = f2bf(v);
                a2h[t][j] = hi;
                a2l[t][j] = f2bf(v - bf2f(hi));
            }
        }
        // ---- layer 2 MFMA ----
        float s_[4] = {0, 0, 0, 0}, s2_[4] = {0, 0, 0, 0};
        float t2[4][4];
        #pragma unroll
        for (int g = 0; g < 4; g++) {
            f32x4 c = {0.f, 0.f, 0.f, 0.f};
            #pragma unroll
            for (int t = 0; t < 2; t++) {
                c = __builtin_amdgcn_mfma_f32_16x16x32_bf16(a2l[t], b2h[g * 2 + t], c, 0, 0, 0);
                c = __builtin_amdgcn_mfma_f32_16x16x32_bf16(a2h[t], b2l[g * 2 + t], c, 0, 0, 0);
                c = __builtin_amdgcn_mfma_f32_16x16x32_bf16(a2h[t], b2h[g * 2 + t], c, 0, 0, 0);
            }
            #pragma unroll
            for (int i = 0; i < 4; i++) {
                float v = c[i] + b2v[g];
                v = fmaxf(v, 0.f);
                t2[g][i] = v;
                s_[i] += v;
                s2_[i] += v * v;
            }
        }
        #pragma unroll
        for (int off = 1; off < 16; off <<= 1) {
            #pragma unroll
            for (int i = 0; i < 4; i++) {
                s_[i] += __shfl_xor(s_[i], off, 64);
                s2_[i] += __shfl_xor(s2_[i], off, 64);
            }
        }
        int dn[4];
        #pragma unroll
        for (int i = 0; i < 4; i++) dn[i] = ei[N_EDGES + e0 + q * 4 + i];
        #pragma unroll
        for (int i = 0; i < 4; i++) {
            float mean = s_[i] * (1.f / 64.f);
            float var = s2_[i] * (1.f / 64.f) - mean * mean;
            float rs = rsqrtf(var + 1e-5f);
            #pragma unroll
            for (int g = 0; g < 4; g++) {
                float z = (t2[g][i] - mean) * rs * gam[g] + bet[g];
                atomicAdd(&h[dn[i] * 64 + g * 16 + m], z);
            }
        }
    }
}

// ---------------- qkv projection: wave per node ----------------
__global__ void qkv_kernel(const float* __restrict__ h, const float* __restrict__ w,
                           const float* __restrict__ b, float* __restrict__ qb,
                           float* __restrict__ kb, float* __restrict__ vb) {
    __shared__ float wl[192 * 65];
    for (int i = threadIdx.x; i < 192 * 64; i += blockDim.x) {
        int r = i >> 6, c = i & 63;
        wl[r * 65 + c] = w[i];
    }
    __syncthreads();
    int lane = threadIdx.x & 63;
    int n = blockIdx.x * 4 + (threadIdx.x >> 6);
    int j = lane;
    float hj = h[n * 64 + j];
    float aq = b[j], ak = b[j + 64], av = b[j + 128];
    #pragma unroll
    for (int k = 0; k < 64; k++) {
        float hk = bcastf(hj, k);
        aq = fmaf(wl[j * 65 + k], hk, aq);
        ak = fmaf(wl[(j + 64) * 65 + k], hk, ak);
        av = fmaf(wl[(j + 128) * 65 + k], hk, av);
    }
    int head = j >> 4, d = j & 15;
    int o = (head * N_NODES + n) * 16 + d;
    qb[o] = aq * 0.25f;  // fold 1/sqrt(16) into q
    kb[o] = ak;
    vb[o] = av;
}

// ---------------- attention phase 1 ----------------
__device__ __forceinline__ float dot16(const float* a, const float* b) {
    float s0 = 0, s1 = 0, s2 = 0, s3 = 0;
    #pragma unroll
    for (int d = 0; d < 16; d += 4) {
        s0 = fmaf(a[d], b[d], s0);
        s1 = fmaf(a[d + 1], b[d + 1], s1);
        s2 = fmaf(a[d + 2], b[d + 2], s2);
        s3 = fmaf(a[d + 3], b[d + 3], s3);
    }
    return (s0 + s1) + (s2 + s3);
}

__device__ __forceinline__ void online_upd(float s, float& m, float& l, float* o,
                                           const float* vrow) {
    if (s > m) {
        float c = __expf(m - s);
        m = s;
        l = l * c + 1.f;
        #pragma unroll
        for (int d = 0; d < 16; d++) o[d] = fmaf(o[d], c, vrow[d]);
    } else {
        float p = __expf(s - m);
        l += p;
        #pragma unroll
        for (int d = 0; d < 16; d++) o[d] = fmaf(p, vrow[d], o[d]);
    }
}

__global__ void attn_p1(const float* __restrict__ qB, const float* __restrict__ kB,
                        const float* __restrict__ vB, float* __restrict__ part) {
    __shared__ float Ks[KTILE][16];
    __shared__ float Vs[KTILE][16];
    int head = blockIdx.x, qt = blockIdx.y, kc = blockIdx.z;
    int t = threadIdx.x;
    int q0 = qt * QTILE + t;
    int q1 = q0 + 256;
    const float* qh = qB + (size_t)head * N_NODES * 16;
    float qa[16], qc[16];
    #pragma unroll
    for (int d4 = 0; d4 < 4; d4++) {
        float4 f = ((const float4*)(qh + q0 * 16))[d4];
        qa[d4 * 4] = f.x; qa[d4 * 4 + 1] = f.y; qa[d4 * 4 + 2] = f.z; qa[d4 * 4 + 3] = f.w;
        float4 g = ((const float4*)(qh + q1 * 16))[d4];
        qc[d4 * 4] = g.x; qc[d4 * 4 + 1] = g.y; qc[d4 * 4 + 2] = g.z; qc[d4 * 4 + 3] = g.w;
    }
    float m0 = -3e38f, l0 = 0.f, o0[16];
    float m1 = -3e38f, l1 = 0.f, o1[16];
    #pragma unroll
    for (int d = 0; d < 16; d++) { o0[d] = 0.f; o1[d] = 0.f; }

    const float* kh = kB + ((size_t)head * N_NODES + kc * KCHUNK) * 16;
    const float* vh = vB + ((size_t)head * N_NODES + kc * KCHUNK) * 16;
    int sr = t >> 2, sc = (t & 3) << 2;

    for (int kt = 0; kt < KCHUNK; kt += KTILE) {
        __syncthreads();
        *(float4*)&Ks[sr][sc] = *(const float4*)&kh[(kt + sr) * 16 + sc];
        *(float4*)&Vs[sr][sc] = *(const float4*)&vh[(kt + sr) * 16 + sc];
        __syncthreads();
        for (int kk = 0; kk < KTILE; kk++) {
            float krow[16], vrow[16];
            #pragma unroll
            for (int d4 = 0; d4 < 4; d4++) {
                float4 kf = ((const float4*)&Ks[kk][0])[d4];
                krow[d4 * 4] = kf.x; krow[d4 * 4 + 1] = kf.y;
                krow[d4 * 4 + 2] = kf.z; krow[d4 * 4 + 3] = kf.w;
                float4 vf = ((const float4*)&Vs[kk][0])[d4];
                vrow[d4 * 4] = vf.x; vrow[d4 * 4 + 1] = vf.y;
                vrow[d4 * 4 + 2] = vf.z; vrow[d4 * 4 + 3] = vf.w;
            }
            float s0 = dot16(qa, krow);
            float s1 = dot16(qc, krow);
            online_upd(s0, m0, l0, o0, vrow);
            online_upd(s1, m1, l1, o1, vrow);
        }
    }
    float* p0 = part + ((size_t)(head * NCHUNK + kc) * N_NODES + q0) * 18;
    float* p1 = part + ((size_t)(head * NCHUNK + kc) * N_NODES + q1) * 18;
    #pragma unroll
    for (int d = 0; d < 16; d++) { p0[d] = o0[d]; p1[d] = o1[d]; }
    p0[16] = m0; p0[17] = l0;
    p1[16] = m1; p1[17] = l1;
}

// ---------------- attention phase 2: merge chunks ----------------
__global__ void attn_merge(const float* __restrict__ part, float* __restrict__ o64) {
    int tid = blockIdx.x * blockDim.x + threadIdx.x;  // 16384
    int head = tid >> 12;
    int qg = tid & 4095;
    float M = -3e38f, L = 0.f, O[16];
    #pragma unroll
    for (int d = 0; d < 16; d++) O[d] = 0.f;
    for (int c = 0; c < NCHUNK; c++) {
        const float* p = part + ((size_t)(head * NCHUNK + c) * N_NODES + qg) * 18;
        float mc = p[16], lc = p[17];
        if (mc > M) {
            float s = __expf(M - mc);
            M = mc;
            L = L * s + lc;
            #pragma unroll
            for (int d = 0; d < 16; d++) O[d] = fmaf(O[d], s, p[d]);
        } else {
            float s = __expf(mc - M);
            L = fmaf(lc, s, L);
            #pragma unroll
            for (int d = 0; d < 16; d++) O[d] = fmaf(p[d], s, O[d]);
        }
    }
    float inv = 1.f / L;
    #pragma unroll
    for (int d = 0; d < 16; d++) o64[qg * 64 + head * 16 + d] = O[d] * inv;
}

// ---------------- out_proj + residual + LN + final linear ----------------
__global__ void post_kernel(const float* __restrict__ h, const float* __restrict__ o64,
                            const float* __restrict__ opw, const float* __restrict__ opb,
                            const float* __restrict__ ag, const float* __restrict__ ab,
                            const float* __restrict__ ow, const float* __restrict__ ob,
                            float* __restrict__ out) {
    __shared__ float wl1[64 * 65];
    __shared__ float wl2[64 * 65];
    for (int i = threadIdx.x; i < 4096; i += blockDim.x) {
        int r = i >> 6, c = i & 63;
        wl1[r * 65 + c] = opw[i];
        wl2[r * 65 + c] = ow[i];
    }
    __syncthreads();
    int lane = threadIdx.x & 63;
    int n = blockIdx.x * 4 + (threadIdx.x >> 6);
    int j = lane;
    float oj = o64[n * 64 + j];
    float acc = opb[j];
    #pragma unroll
    for (int k = 0; k < 64; k++) acc = fmaf(wl1[j * 65 + k], bcastf(oj, k), acc);
    float r = h[n * 64 + j] + acc;
    float s = r, s2 = r * r;
    wave_sum2(s, s2);
    float mean = s * (1.f / 64.f);
    float var = s2 * (1.f / 64.f) - mean * mean;
    float hn = (r - mean) * rsqrtf(var + 1e-5f) * ag[j] + ab[j];
    float acc2 = ob[j];
    #pragma unroll
    for (int k = 0; k < 64; k++) acc2 = fmaf(wl2[j * 65 + k], bcastf(hn, k), acc2);
    out[n * 64 + j] = acc2;
}

extern "C" void kernel_launch(void* const* d_in, const int* in_sizes, int n_in,
                              void* d_out, int out_size, void* d_ws, size_t ws_size,
                              hipStream_t stream) {
    const float* x        = (const float*)d_in[0];
    const float* edge_attr= (const float*)d_in[1];
    const float* emb      = (const float*)d_in[2];
    const float* lin1_w   = (const float*)d_in[3];
    const float* lin1_b   = (const float*)d_in[4];
    const float* lay_w    = (const float*)d_in[5];
    const float* lay_b    = (const float*)d_in[6];
    const float* ln_g     = (const float*)d_in[7];
    const float* ln_b     = (const float*)d_in[8];
    const float* ipw      = (const float*)d_in[9];
    const float* ipb      = (const float*)d_in[10];
    const float* opw      = (const float*)d_in[11];
    const float* opb      = (const float*)d_in[12];
    const float* ang      = (const float*)d_in[13];
    const float* anb      = (const float*)d_in[14];
    const float* ow       = (const float*)d_in[15];
    const float* ob       = (const float*)d_in[16];
    const int*   ei       = (const int*)d_in[17];
    const int*   et       = (const int*)d_in[18];

    char* wsb = (char*)d_ws;
    unsigned short* xe_hi = (unsigned short*)wsb;            // 65536 elems
    unsigned short* xe_lo = xe_hi + 65536;                   // 65536 elems
    float* h    = (float*)(wsb + 262144);                    // 262144 floats
    float* qb   = h + 262144;
    float* kb   = qb + 262144;
    float* vb   = kb + 262144;
    float* o64  = vb + 262144;
    float* part = o64 + 262144;                              // 4*16*4096*18

    hipMemsetAsync(h, 0, 262144 * sizeof(float), stream);
    xe16_kernel<<<256, 256, 0, stream>>>(x, emb, et, xe_hi, xe_lo);
    edge_mfma<<<512, 256, 0, stream>>>(xe_hi, xe_lo, edge_attr, ei, lin1_w, lin1_b,
                                       lay_w, lay_b, ln_g, ln_b, h);
    qkv_kernel<<<1024, 256, 0, stream>>>(h, ipw, ipb, qb, kb, vb);
    attn_p1<<<dim3(4, 8, 16), 256, 0, stream>>>(qb, kb, vb, part);
    attn_merge<<<64, 256, 0, stream>>>(part, o64);
    post_kernel<<<1024, 256, 0, stream>>>(h, o64, opw, opb, ang, anb, ow, ob,
                                          (float*)d_out);
}

// Round 4
// 325.212 us; speedup vs baseline: 1.6274x; 1.1057x over previous
//
#include <hip/hip_runtime.h>

#define N_NODES 4096
#define N_EDGES 524288
#define HID 64

typedef short short8 __attribute__((ext_vector_type(8)));
typedef float f32x4 __attribute__((ext_vector_type(4)));

__device__ __forceinline__ float bcastf(float v, int l) {
    return __int_as_float(__builtin_amdgcn_readlane(__float_as_int(v), l));
}

__device__ __forceinline__ void wave_sum2(float& a, float& b) {
    #pragma unroll
    for (int off = 32; off > 0; off >>= 1) {
        a += __shfl_xor(a, off, 64);
        b += __shfl_xor(b, off, 64);
    }
}

__device__ __forceinline__ short f2bf(float f) {
    unsigned u = __float_as_uint(f);
    u = u + 0x7FFFu + ((u >> 16) & 1u);
    return (short)(u >> 16);
}
__device__ __forceinline__ float bf2f(short s) {
    return __uint_as_float(((unsigned)(unsigned short)s) << 16);
}

// ---------------- xe hi/lo bf16 planes ----------------
__global__ void xe16_kernel(const float* __restrict__ x, const float* __restrict__ emb,
                            const int* __restrict__ etype,
                            unsigned short* __restrict__ xh, unsigned short* __restrict__ xl) {
    int tid = blockIdx.x * blockDim.x + threadIdx.x;
    if (tid >= N_NODES * 16) return;
    int n = tid >> 4, i = tid & 15;
    float v = 0.f;
    if (i < 6) v = x[n * 6 + i];
    else if (i < 14) v = emb[etype[n] * 8 + (i - 6)];
    short hi = f2bf(v);
    short lo = f2bf(v - bf2f(hi));
    xh[tid] = (unsigned short)hi;
    xl[tid] = (unsigned short)lo;
}

// ---------------- edge MLP via MFMA, 2048 blocks, prefetched ----------------
__global__ void __launch_bounds__(256) edge_mfma(
        const unsigned short* __restrict__ xh, const unsigned short* __restrict__ xl,
        const float* __restrict__ edge_attr, const int* __restrict__ ei,
        const float* __restrict__ w1, const float* __restrict__ b1,
        const float* __restrict__ w2, const float* __restrict__ b2,
        const float* __restrict__ lg, const float* __restrict__ lb,
        float* __restrict__ h) {
    __shared__ float Y[4][16 * 68];
    int lane = threadIdx.x & 63;
    int wv = threadIdx.x >> 6;
    int m = lane & 15;
    int q = lane >> 4;
    float* Yw = Y[wv];

    short8 b1h[4], b1l[4];
    float w14[4], b1v[4], b2v[4], gam[4], bet[4];
    #pragma unroll
    for (int g = 0; g < 4; g++) {
        int row = g * 16 + m;
        #pragma unroll
        for (int j = 0; j < 8; j++) {
            int k = q * 8 + j;
            float w = (k < 15) ? w1[row * 15 + k] : 0.f;
            short hi = f2bf(w);
            b1h[g][j] = hi;
            b1l[g][j] = f2bf(w - bf2f(hi));
        }
        w14[g] = w1[row * 15 + 14];
        b1v[g] = b1[row];
        b2v[g] = b2[row];
        gam[g] = lg[row];
        bet[g] = lb[row];
    }
    short8 b2h[8], b2l[8];
    #pragma unroll
    for (int g = 0; g < 4; g++) {
        #pragma unroll
        for (int t = 0; t < 2; t++) {
            int idx = g * 2 + t;
            #pragma unroll
            for (int j = 0; j < 8; j++) {
                float w = w2[(g * 16 + m) * 64 + t * 32 + q * 8 + j];
                short hi = f2bf(w);
                b2h[idx][j] = hi;
                b2l[idx][j] = f2bf(w - bf2f(hi));
            }
        }
    }

    int wgid = blockIdx.x * 4 + wv;   // 0..8191
    int e0 = wgid * 16;
    int srcn = ei[e0 + m];
    short8 a1h = (short8)0, a1l = (short8)0;
    if (q < 2) {
        a1h = *(const short8*)(xh + srcn * 16 + q * 8);
        a1l = *(const short8*)(xl + srcn * 16 + q * 8);
    }
    float ea[4];
    #pragma unroll
    for (int i = 0; i < 4; i++) ea[i] = edge_attr[e0 + q * 4 + i];

    #pragma unroll
    for (int it = 0; it < 4; it++) {
        // ---- prefetch next tile ----
        int e0n = e0 + 8192 * 16;
        short8 a1h2 = (short8)0, a1l2 = (short8)0;
        float ea2[4] = {0, 0, 0, 0};
        if (it < 3) {
            int srcn2 = ei[e0n + m];
            if (q < 2) {
                a1h2 = *(const short8*)(xh + srcn2 * 16 + q * 8);
                a1l2 = *(const short8*)(xl + srcn2 * 16 + q * 8);
            }
            #pragma unroll
            for (int i = 0; i < 4; i++) ea2[i] = edge_attr[e0n + q * 4 + i];
        }
        // ---- layer 1 ----
        f32x4 c1[4];
        #pragma unroll
        for (int g = 0; g < 4; g++) {
            f32x4 c = {0.f, 0.f, 0.f, 0.f};
            c = __builtin_amdgcn_mfma_f32_16x16x32_bf16(a1l, b1h[g], c, 0, 0, 0);
            c = __builtin_amdgcn_mfma_f32_16x16x32_bf16(a1h, b1l[g], c, 0, 0, 0);
            c = __builtin_amdgcn_mfma_f32_16x16x32_bf16(a1h, b1h[g], c, 0, 0, 0);
            c1[g] = c;
        }
        float s[4] = {0, 0, 0, 0}, s2[4] = {0, 0, 0, 0};
        float t1[4][4];
        #pragma unroll
        for (int g = 0; g < 4; g++) {
            #pragma unroll
            for (int i = 0; i < 4; i++) {
                float v = c1[g][i] + b1v[g] + w14[g] * ea[i];
                v = fmaxf(v, 0.f);
                t1[g][i] = v;
                s[i] += v;
                s2[i] += v * v;
            }
        }
        #pragma unroll
        for (int off = 1; off < 16; off <<= 1) {
            #pragma unroll
            for (int i = 0; i < 4; i++) {
                s[i] += __shfl_xor(s[i], off, 64);
                s2[i] += __shfl_xor(s2[i], off, 64);
            }
        }
        #pragma unroll
        for (int i = 0; i < 4; i++) {
            float mean = s[i] * (1.f / 64.f);
            float var = s2[i] * (1.f / 64.f) - mean * mean;
            s[i] = mean;
            s2[i] = rsqrtf(var + 1e-5f);
        }
        #pragma unroll
        for (int g = 0; g < 4; g++) {
            #pragma unroll
            for (int i = 0; i < 4; i++) {
                float y = (t1[g][i] - s[i]) * s2[i] * gam[g] + bet[g];
                Yw[(q * 4 + i) * 68 + g * 16 + m] = y;
            }
        }
        short8 a2h[2], a2l[2];
        #pragma unroll
        for (int t = 0; t < 2; t++) {
            #pragma unroll
            for (int j = 0; j < 8; j++) {
                float v = Yw[m * 68 + t * 32 + q * 8 + j];
                short hi = f2bf(v);
                a2h[t][j] = hi;
                a2l[t][j] = f2bf(v - bf2f(hi));
            }
        }
        float s_[4] = {0, 0, 0, 0}, s2_[4] = {0, 0, 0, 0};
        float t2[4][4];
        #pragma unroll
        for (int g = 0; g < 4; g++) {
            f32x4 c = {0.f, 0.f, 0.f, 0.f};
            #pragma unroll
            for (int t = 0; t < 2; t++) {
                c = __builtin_amdgcn_mfma_f32_16x16x32_bf16(a2l[t], b2h[g * 2 + t], c, 0, 0, 0);
                c = __builtin_amdgcn_mfma_f32_16x16x32_bf16(a2h[t], b2l[g * 2 + t], c, 0, 0, 0);
                c = __builtin_amdgcn_mfma_f32_16x16x32_bf16(a2h[t], b2h[g * 2 + t], c, 0, 0, 0);
            }
            #pragma unroll
            for (int i = 0; i < 4; i++) {
                float v = c[i] + b2v[g];
                v = fmaxf(v, 0.f);
                t2[g][i] = v;
                s_[i] += v;
                s2_[i] += v * v;
            }
        }
        #pragma unroll
        for (int off = 1; off < 16; off <<= 1) {
            #pragma unroll
            for (int i = 0; i < 4; i++) {
                s_[i] += __shfl_xor(s_[i], off, 64);
                s2_[i] += __shfl_xor(s2_[i], off, 64);
            }
        }
        int dn[4];
        #pragma unroll
        for (int i = 0; i < 4; i++) dn[i] = ei[N_EDGES + e0 + q * 4 + i];
        #pragma unroll
        for (int i = 0; i < 4; i++) {
            float mean = s_[i] * (1.f / 64.f);
            float var = s2_[i] * (1.f / 64.f) - mean * mean;
            float rs = rsqrtf(var + 1e-5f);
            #pragma unroll
            for (int g = 0; g < 4; g++) {
                float z = (t2[g][i] - mean) * rs * gam[g] + bet[g];
                atomicAdd(&h[dn[i] * 64 + g * 16 + m], z);
            }
        }
        e0 = e0n;
        a1h = a1h2; a1l = a1l2;
        #pragma unroll
        for (int i = 0; i < 4; i++) ea[i] = ea2[i];
    }
}

// ---------------- qkv projection -> bf16 planes (q,k hi/lo; vT single) ----------------
__global__ void qkv_kernel(const float* __restrict__ h, const float* __restrict__ w,
                           const float* __restrict__ b,
                           unsigned short* __restrict__ qhp, unsigned short* __restrict__ qlp,
                           unsigned short* __restrict__ khp, unsigned short* __restrict__ klp,
                           unsigned short* __restrict__ vT) {
    __shared__ float wl[192 * 65];
    __shared__ unsigned short vs[256];
    for (int i = threadIdx.x; i < 192 * 64; i += blockDim.x) {
        int r = i >> 6, c = i & 63;
        wl[r * 65 + c] = w[i];
    }
    __syncthreads();
    int lane = threadIdx.x & 63;
    int wv = threadIdx.x >> 6;
    int n = blockIdx.x * 4 + wv;
    int j = lane;
    float hj = h[n * 64 + j];
    float aq = b[j], ak = b[j + 64], av = b[j + 128];
    #pragma unroll
    for (int k = 0; k < 64; k++) {
        float hk = bcastf(hj, k);
        aq = fmaf(wl[j * 65 + k], hk, aq);
        ak = fmaf(wl[(j + 64) * 65 + k], hk, ak);
        av = fmaf(wl[(j + 128) * 65 + k], hk, av);
    }
    aq *= 0.25f;  // 1/sqrt(16)
    int head = j >> 4, d = j & 15;
    size_t idx = ((size_t)(head * N_NODES + n)) * 16 + d;
    short qhi = f2bf(aq);
    qhp[idx] = (unsigned short)qhi;
    qlp[idx] = (unsigned short)f2bf(aq - bf2f(qhi));
    short khi = f2bf(ak);
    khp[idx] = (unsigned short)khi;
    klp[idx] = (unsigned short)f2bf(ak - bf2f(khi));
    vs[threadIdx.x] = (unsigned short)f2bf(av);   // layout: vs[node_in_block*64 + feat]
    __syncthreads();
    int t = threadIdx.x;
    int f = t >> 2, c = t & 3;
    // FIX (R3 bug): vs is [node][feat], so V[node c][feat f] = vs[c*64 + f]
    vT[(size_t)f * N_NODES + blockIdx.x * 4 + c] = vs[c * 64 + f];
}

// ---------------- attention via MFMA: wave = (head, 16-q tile, 512-key chunk) ----------------
__global__ void __launch_bounds__(256) attn_mfma(
        const unsigned short* __restrict__ qhp, const unsigned short* __restrict__ qlp,
        const unsigned short* __restrict__ khp, const unsigned short* __restrict__ klp,
        const unsigned short* __restrict__ vT,
        float* __restrict__ part_o, float* __restrict__ part_ml) {
    __shared__ unsigned short Pl[4][16 * 72];
    int lane = threadIdx.x & 63;
    int wv = threadIdx.x >> 6;
    int m = lane & 15;
    int g = lane >> 4;
    unsigned short* Pw = Pl[wv];

    int wid = blockIdx.x * 4 + wv;     // 0..8191
    int kc = wid & 7;
    int qt = (wid >> 3) & 255;
    int head = wid >> 11;

    short8 aqh = (short8)0, aql = (short8)0;
    if (g < 2) {
        size_t qi = ((size_t)(head * N_NODES + qt * 16 + m)) * 16 + g * 8;
        aqh = *(const short8*)(qhp + qi);
        aql = *(const short8*)(qlp + qi);
    }
    float mS[4], lS[4];
    #pragma unroll
    for (int r = 0; r < 4; r++) { mS[r] = -3e38f; lS[r] = 0.f; }
    f32x4 Ot = {0.f, 0.f, 0.f, 0.f};

    const unsigned short* khb = khp + (size_t)head * N_NODES * 16;
    const unsigned short* klb = klp + (size_t)head * N_NODES * 16;
    const unsigned short* vtb = vT + (size_t)(head * 16 + m) * N_NODES;

    for (int bblk = 0; bblk < 8; bblk++) {
        int n0 = kc * 512 + bblk * 64;
        // ---- scores for 4 sub-tiles of 16 keys ----
        f32x4 S[4];
        #pragma unroll
        for (int s = 0; s < 4; s++) {
            short8 bkh = (short8)0, bkl = (short8)0;
            if (g < 2) {
                size_t ki = ((size_t)(n0 + s * 16 + m)) * 16 + g * 8;
                bkh = *(const short8*)(khb + ki);
                bkl = *(const short8*)(klb + ki);
            }
            f32x4 c = {0.f, 0.f, 0.f, 0.f};
            c = __builtin_amdgcn_mfma_f32_16x16x32_bf16(aqh, bkl, c, 0, 0, 0);
            c = __builtin_amdgcn_mfma_f32_16x16x32_bf16(aql, bkh, c, 0, 0, 0);
            c = __builtin_amdgcn_mfma_f32_16x16x32_bf16(aqh, bkh, c, 0, 0, 0);
            S[s] = c;
        }
        // ---- online softmax (rows=q as (g,r), cols=key across 16 lanes x 4 subtiles) ----
        float mr[4];
        #pragma unroll
        for (int r = 0; r < 4; r++)
            mr[r] = fmaxf(fmaxf(S[0][r], S[1][r]), fmaxf(S[2][r], S[3][r]));
        #pragma unroll
        for (int off = 1; off < 16; off <<= 1)
            #pragma unroll
            for (int r = 0; r < 4; r++) mr[r] = fmaxf(mr[r], __shfl_xor(mr[r], off, 64));
        float alpha[4];
        #pragma unroll
        for (int r = 0; r < 4; r++) {
            float mn = fmaxf(mS[r], mr[r]);
            alpha[r] = __expf(mS[r] - mn);
            mS[r] = mn;
        }
        float ls[4] = {0, 0, 0, 0};
        #pragma unroll
        for (int s = 0; s < 4; s++) {
            #pragma unroll
            for (int r = 0; r < 4; r++) {
                float p = __expf(S[s][r] - mS[r]);
                ls[r] += p;
                Pw[(g * 4 + r) * 72 + s * 16 + m] = (unsigned short)f2bf(p);
            }
        }
        #pragma unroll
        for (int off = 1; off < 16; off <<= 1)
            #pragma unroll
            for (int r = 0; r < 4; r++) ls[r] += __shfl_xor(ls[r], off, 64);
        #pragma unroll
        for (int r = 0; r < 4; r++) lS[r] = lS[r] * alpha[r] + ls[r];
        // ---- broadcast alpha[q] to lane holding O^T col q=m ----
        int sel = lane & 3;
        float a01 = (sel & 1) ? alpha[1] : alpha[0];
        float a23 = (sel & 1) ? alpha[3] : alpha[2];
        float aown = (sel & 2) ? a23 : a01;
        int srcl = ((m >> 2) << 4) | (m & 3);
        float ab = __int_as_float(__builtin_amdgcn_ds_bpermute(srcl << 2, __float_as_int(aown)));
        #pragma unroll
        for (int r = 0; r < 4; r++) Ot[r] *= ab;
        // ---- O^T += V^T * P^T over 64 keys (2 MFMA of K=32) ----
        #pragma unroll
        for (int t = 0; t < 2; t++) {
            short8 avf = *(const short8*)(vtb + n0 + t * 32 + g * 8);
            short8 bpf = *(const short8*)(Pw + m * 72 + t * 32 + g * 8);
            Ot = __builtin_amdgcn_mfma_f32_16x16x32_bf16(avf, bpf, Ot, 0, 0, 0);
        }
    }
    // ---- store partials ----
    size_t pb = ((size_t)(head * 8 + kc) * 256 + qt) * 256;
    *(f32x4*)(part_o + pb + m * 16 + g * 4) = Ot;
    if (m == 0) {
        size_t mb = ((size_t)(head * 8 + kc) * 256 + qt) * 32;
        #pragma unroll
        for (int r = 0; r < 4; r++) {
            part_ml[mb + g * 4 + r] = mS[r];
            part_ml[mb + 16 + g * 4 + r] = lS[r];
        }
    }
}

// ---------------- attention merge: thread per (head, q) ----------------
__global__ void attn_merge(const float* __restrict__ part_o, const float* __restrict__ part_ml,
                           float* __restrict__ o64) {
    int tid = blockIdx.x * blockDim.x + threadIdx.x;  // 16384
    int head = tid >> 12;
    int qg = tid & 4095;
    int qt = qg >> 4, qi = qg & 15;
    float M = -3e38f, L = 0.f, O[16];
    #pragma unroll
    for (int d = 0; d < 16; d++) O[d] = 0.f;
    for (int c = 0; c < 8; c++) {
        size_t base = ((size_t)(head * 8 + c) * 256 + qt);
        const float* po = part_o + base * 256 + qi * 16;
        float mc = part_ml[base * 32 + qi];
        float lc = part_ml[base * 32 + 16 + qi];
        if (mc > M) {
            float s = __expf(M - mc);
            M = mc;
            L = L * s + lc;
            #pragma unroll
            for (int d = 0; d < 16; d++) O[d] = fmaf(O[d], s, po[d]);
        } else {
            float s = __expf(mc - M);
            L = fmaf(lc, s, L);
            #pragma unroll
            for (int d = 0; d < 16; d++) O[d] = fmaf(po[d], s, O[d]);
        }
    }
    float inv = 1.f / L;
    #pragma unroll
    for (int d = 0; d < 16; d++) o64[(size_t)qg * 64 + head * 16 + d] = O[d] * inv;
}

// ---------------- out_proj + residual + LN + final linear ----------------
__global__ void post_kernel(const float* __restrict__ h, const float* __restrict__ o64,
                            const float* __restrict__ opw, const float* __restrict__ opb,
                            const float* __restrict__ ag, const float* __restrict__ ab,
                            const float* __restrict__ ow, const float* __restrict__ ob,
                            float* __restrict__ out) {
    __shared__ float wl1[64 * 65];
    __shared__ float wl2[64 * 65];
    for (int i = threadIdx.x; i < 4096; i += blockDim.x) {
        int r = i >> 6, c = i & 63;
        wl1[r * 65 + c] = opw[i];
        wl2[r * 65 + c] = ow[i];
    }
    __syncthreads();
    int lane = threadIdx.x & 63;
    int n = blockIdx.x * 4 + (threadIdx.x >> 6);
    int j = lane;
    float oj = o64[n * 64 + j];
    float acc = opb[j];
    #pragma unroll
    for (int k = 0; k < 64; k++) acc = fmaf(wl1[j * 65 + k], bcastf(oj, k), acc);
    float r = h[n * 64 + j] + acc;
    float s = r, s2 = r * r;
    wave_sum2(s, s2);
    float mean = s * (1.f / 64.f);
    float var = s2 * (1.f / 64.f) - mean * mean;
    float hn = (r - mean) * rsqrtf(var + 1e-5f) * ag[j] + ab[j];
    float acc2 = ob[j];
    #pragma unroll
    for (int k = 0; k < 64; k++) acc2 = fmaf(wl2[j * 65 + k], bcastf(hn, k), acc2);
    out[n * 64 + j] = acc2;
}

extern "C" void kernel_launch(void* const* d_in, const int* in_sizes, int n_in,
                              void* d_out, int out_size, void* d_ws, size_t ws_size,
                              hipStream_t stream) {
    const float* x        = (const float*)d_in[0];
    const float* edge_attr= (const float*)d_in[1];
    const float* emb      = (const float*)d_in[2];
    const float* lin1_w   = (const float*)d_in[3];
    const float* lin1_b   = (const float*)d_in[4];
    const float* lay_w    = (const float*)d_in[5];
    const float* lay_b    = (const float*)d_in[6];
    const float* ln_g     = (const float*)d_in[7];
    const float* ln_b     = (const float*)d_in[8];
    const float* ipw      = (const float*)d_in[9];
    const float* ipb      = (const float*)d_in[10];
    const float* opw      = (const float*)d_in[11];
    const float* opb      = (const float*)d_in[12];
    const float* ang      = (const float*)d_in[13];
    const float* anb      = (const float*)d_in[14];
    const float* ow       = (const float*)d_in[15];
    const float* ob       = (const float*)d_in[16];
    const int*   ei       = (const int*)d_in[17];
    const int*   et       = (const int*)d_in[18];

    char* wsb = (char*)d_ws;
    size_t off = 0;
    unsigned short* xe_hi = (unsigned short*)(wsb + off); off += 131072;
    unsigned short* xe_lo = (unsigned short*)(wsb + off); off += 131072;
    float* h              = (float*)(wsb + off);          off += 1048576;
    unsigned short* qhp   = (unsigned short*)(wsb + off); off += 524288;
    unsigned short* qlp   = (unsigned short*)(wsb + off); off += 524288;
    unsigned short* khp   = (unsigned short*)(wsb + off); off += 524288;
    unsigned short* klp   = (unsigned short*)(wsb + off); off += 524288;
    unsigned short* vT    = (unsigned short*)(wsb + off); off += 524288;
    float* o64            = (float*)(wsb + off);          off += 1048576;
    float* part_o         = (float*)(wsb + off);          off += 8388608;
    float* part_ml        = (float*)(wsb + off);          off += 1048576;

    hipMemsetAsync(h, 0, 1048576, stream);
    xe16_kernel<<<256, 256, 0, stream>>>(x, emb, et, xe_hi, xe_lo);
    edge_mfma<<<2048, 256, 0, stream>>>(xe_hi, xe_lo, edge_attr, ei, lin1_w, lin1_b,
                                        lay_w, lay_b, ln_g, ln_b, h);
    qkv_kernel<<<1024, 256, 0, stream>>>(h, ipw, ipb, qhp, qlp, khp, klp, vT);
    attn_mfma<<<2048, 256, 0, stream>>>(qhp, qlp, khp, klp, vT, part_o, part_ml);
    attn_merge<<<64, 256, 0, stream>>>(part_o, part_ml, o64);
    post_kernel<<<1024, 256, 0, stream>>>(h, o64, opw, opb, ang, anb, ow, ob,
                                          (float*)d_out);
}